// Round 14
// baseline (465.677 us; speedup 1.0000x reference)
//
#include <hip/hip_runtime.h>
#include <math.h>

#define BB 4
#define NN1 4096
#define NN2 1024
#define DS 128
#define DD 64
#define DOUT 256
#define M1 16384        // BB*NN1
#define MH 262144       // M1*16
#define KCAT 192        // DS+DD
#define KI 8            // interp k
#define KN 16           // neighbor k

#define OUT_P1 49152
#define OUT_X  49152
#define OUT_O1 4243456

#define KSCALE 268435456.f   // 2^28: fixed-point key scale for d^2 (<4)

// grid-kNN params
#define GC 8
#define GH 0.125f
#define NCELL 512       // GC^3
#define LCAP 512        // per-wave candidate list capacity

// ---- workspace layout (float offsets) ----
static const size_t OFF_HPRE = 0;                      // bf16 MH*DS
static const size_t OFF_WTS  = 16777216;               // swizzled weights (hi/lo)
static const size_t OFF_TMP  = 33554432;
static const size_t OFF_XD   = OFF_TMP  + 2097152;
static const size_t OFF_XI   = OFF_XD   + 2097152;
static const size_t OFF_Q    = OFF_XI   + 2097152;     // bf16 q
static const size_t OFF_K    = OFF_Q    + 2097152;     // bf16 e = xd - k
static const size_t OFF_V    = OFF_K    + 2097152;     // bf16 v2 = v + xd
static const size_t OFF_OUTP = OFF_V    + 2097152;
static const size_t OFF_NIDX = OFF_OUTP + 4194304;
static const size_t OFF_STAT = OFF_NIDX + 262144;      // 3072 floats
static const size_t OFF_P1Q  = OFF_STAT + 4096;        // 16384 float4
static const size_t OFF_P2Q  = OFF_P1Q  + 65536;       // 4096 float4
static const size_t OFF_SPTS = OFF_P2Q  + 16384;       // sorted float4 (16384)
static const size_t OFF_SIDX = OFF_SPTS + 65536;       // sorted idx (16384 ints)
static const size_t OFF_CST  = OFF_SIDX + 16384;       // CSR starts 4*(512+1)

// ushort offsets inside the weights region
#define WDH 0
#define WDL 8192
#define WQH 16384
#define WQL 32768
#define WKH 49152
#define WKL 65536
#define WVH 81920
#define WVL 98304
#define W1H 114688
#define W1L 131072
#define W2H 147456
#define W2L 163840
#define WOH 180224
#define WOL 229376

typedef __attribute__((ext_vector_type(8))) short short8;
typedef __attribute__((ext_vector_type(4))) float floatx4;

__device__ inline unsigned short f2bf(float f) {
    union { float f; unsigned int u; } x; x.f = f;
    unsigned int r = x.u + 0x7fffu + ((x.u >> 16) & 1u);
    return (unsigned short)(r >> 16);
}
__device__ inline float bf2f(unsigned short h) {
    union { unsigned int u; float f; } x; x.u = ((unsigned int)h) << 16;
    return x.f;
}
__device__ inline unsigned long long shfl_xor_u64(unsigned long long v, int m) {
    unsigned lo = (unsigned)v, hi = (unsigned)(v >> 32);
    lo = (unsigned)__shfl_xor((int)lo, m);
    hi = (unsigned)__shfl_xor((int)hi, m);
    return ((unsigned long long)hi << 32) | lo;
}

// --------- prolog + swizzle merged: copyout, stat zero, point pack, W swizzle
#define PRO_STAT  (OUT_P1 + BB)          // 49156
#define PRO_PACK  (PRO_STAT + 3072)      // 52228
#define PRO_TOTAL (PRO_PACK + M1 + BB*NN2)   // 72708
#define NPRO 285
struct SwzParams {
    const float* W[7];
    unsigned short* hi[7];
    unsigned short* lo[7];
    int N[7];
    int fid0[8];
};
__global__ __launch_bounds__(256) void k_prolog(
    const float* __restrict__ p1, const int* __restrict__ o1,
    const float* __restrict__ p2, float* __restrict__ out,
    float* __restrict__ stat, float4* __restrict__ p1q,
    float4* __restrict__ p2q, SwzParams p)
{
    if (blockIdx.x < NPRO) {
        int i = blockIdx.x * 256 + threadIdx.x;
        if (i < OUT_P1) out[i] = p1[i];
        else if (i < PRO_STAT) out[OUT_O1 + (i - OUT_P1)] = (float)o1[i - OUT_P1];
        else if (i < PRO_PACK) stat[i - PRO_STAT] = 0.f;
        else if (i < PRO_TOTAL) {
            int j = i - PRO_PACK;
            const float* src; float4* dst; int jj;
            if (j < M1) { src = p1; dst = p1q; jj = j; }
            else        { src = p2; dst = p2q; jj = j - M1; }
            float x = src[jj*3+0], y = src[jj*3+1], z = src[jj*3+2];
            float n = fmaf(z, z, fmaf(y, y, x*x));
            dst[jj] = make_float4(x, y, z, n);
        }
        return;
    }
    int fid = (blockIdx.x - NPRO)*4 + (threadIdx.x >> 6);
    int lane = threadIdx.x & 63;
    if (fid >= 272) return;
    int seg = 0;
    #pragma unroll
    for (int i = 1; i < 7; i++) if (fid >= p.fid0[i]) seg = i;
    int f = fid - p.fid0[seg];
    const float* W = p.W[seg];
    int N = p.N[seg];
    int ncj = N >> 4;
    int slab = f / ncj, cj = f - slab*ncj;
    int n  = cj*16 + (lane & 15);
    int k0 = slab*32 + (lane >> 4)*8;
    unsigned int oh[8], ol[8];
    #pragma unroll
    for (int j = 0; j < 8; j++) {
        float v = W[(size_t)(k0 + j) * N + n];
        unsigned short h = f2bf(v);
        oh[j] = h;
        ol[j] = f2bf(v - bf2f(h));
    }
    uint4 ph, pl;
    ph.x = oh[0] | (oh[1] << 16); ph.y = oh[2] | (oh[3] << 16);
    ph.z = oh[4] | (oh[5] << 16); ph.w = oh[6] | (oh[7] << 16);
    pl.x = ol[0] | (ol[1] << 16); pl.y = ol[2] | (ol[3] << 16);
    pl.z = ol[4] | (ol[5] << 16); pl.w = ol[6] | (ol[7] << 16);
    ((uint4*)p.hi[seg])[f*64 + lane] = ph;
    ((uint4*)p.lo[seg])[f*64 + lane] = pl;
}

// --------------------------- grid binning (counting sort), 1 block per batch
__global__ __launch_bounds__(256) void k_bin(
    const float* __restrict__ p1, float4* __restrict__ spts,
    int* __restrict__ sidxA, int* __restrict__ cst)
{
    __shared__ unsigned sa[NCELL], sb[NCELL];
    const int b = blockIdx.x, t = threadIdx.x;
    const float* pb = p1 + (size_t)b*NN1*3;
    for (int i = t; i < NCELL; i += 256) sa[i] = 0u;
    __syncthreads();
    for (int j = t; j < NN1; j += 256) {
        float x = pb[j*3+0], y = pb[j*3+1], z = pb[j*3+2];
        int cx = min(GC-1, max(0, (int)(x*(float)GC)));
        int cy = min(GC-1, max(0, (int)(y*(float)GC)));
        int cz = min(GC-1, max(0, (int)(z*(float)GC)));
        atomicAdd(&sa[cx + GC*(cy + GC*cz)], 1u);
    }
    __syncthreads();
    unsigned* src = sa; unsigned* dst = sb;
    for (int d = 1; d < NCELL; d <<= 1) {
        for (int i = t; i < NCELL; i += 256)
            dst[i] = src[i] + ((i >= d) ? src[i-d] : 0u);
        __syncthreads();
        unsigned* tmp = src; src = dst; dst = tmp;
    }
    for (int i = t; i < NCELL; i += 256) {
        unsigned st = (i == 0) ? 0u : src[i-1];
        cst[b*(NCELL+1) + i] = (int)st;
        dst[i] = st;                       // scatter cursor
    }
    if (t == 0) cst[b*(NCELL+1) + NCELL] = NN1;
    __syncthreads();
    for (int j = t; j < NN1; j += 256) {
        float x = pb[j*3+0], y = pb[j*3+1], z = pb[j*3+2];
        int cx = min(GC-1, max(0, (int)(x*(float)GC)));
        int cy = min(GC-1, max(0, (int)(y*(float)GC)));
        int cz = min(GC-1, max(0, (int)(z*(float)GC)));
        int cid = cx + GC*(cy + GC*cz);
        int pos = (int)atomicAdd(&dst[cid], 1u);
        float n = fmaf(z, z, fmaf(y, y, x*x));
        spts[(size_t)b*NN1 + pos] = make_float4(x, y, z, n);
        sidxA[(size_t)b*NN1 + pos] = j;
    }
}

// wave-level exact top-16 of lst[0..total) as (d2bits,idx) u64 ascending
__device__ inline void wave_top16(const unsigned long long* lst, int total,
                                  unsigned long long* o16, int lane)
{
    unsigned long long kv[8];
    #pragma unroll
    for (int s = 0; s < 8; s++) {
        int ii = lane + 64*s;
        kv[s] = (ii < total) ? lst[ii] : ~0ull;
    }
    for (int r = 0; r < KN; r++) {
        unsigned long long mn = ~0ull; int msl = 0;
        #pragma unroll
        for (int s = 0; s < 8; s++) if (kv[s] < mn) { mn = kv[s]; msl = s; }
        unsigned long long m2 = mn;
        #pragma unroll
        for (int o = 1; o < 64; o <<= 1) {
            unsigned long long p = shfl_xor_u64(m2, o);
            if (p < m2) m2 = p;
        }
        unsigned long long bal = __ballot(mn == m2);
        int srcl = (int)__ffsll(bal) - 1;
        bool im = (lane == srcl);
        #pragma unroll
        for (int s = 0; s < 8; s++) if (im && s == msl) kv[s] = ~0ull;
        if (lane == 0) o16[r] = m2;
    }
}

// --------------------- grid kNN: 1 wave per query, exact with boundary check
__global__ __launch_bounds__(256) void k_knn_grid(
    const float4* __restrict__ p1q, const float4* __restrict__ spts,
    const int* __restrict__ sidxA, const int* __restrict__ cst,
    int* __restrict__ nidx)
{
    __shared__ unsigned long long lsts[4][LCAP];
    __shared__ unsigned long long outs[4][KN];
    const int t = threadIdx.x, wv = t >> 6, lane = t & 63;
    const int gp = blockIdx.x*4 + wv;
    const int b = gp >> 12;
    unsigned long long* lst = lsts[wv];
    unsigned long long* o16 = outs[wv];
    const float4 qv = p1q[gp];
    const float4* sp = spts + (size_t)b*NN1;
    const int* si = sidxA + (size_t)b*NN1;
    const int* cs = cst + b*(NCELL+1);

    const int cx = min(GC-1, max(0, (int)(qv.x*(float)GC)));
    const int cy = min(GC-1, max(0, (int)(qv.y*(float)GC)));
    const int cz = min(GC-1, max(0, (int)(qv.z*(float)GC)));
    const int x0 = max(0, cx-1), x1 = min(GC-1, cx+1);
    const int y0 = max(0, cy-1), y1 = min(GC-1, cy+1);
    const int z0 = max(0, cz-1), z1 = min(GC-1, cz+1);
    const int nx = x1-x0+1, ny = y1-y0+1, nz = z1-z0+1;
    const int ncells = nx*ny*nz;

    int myStart = 0, myCnt = 0;
    if (lane < ncells) {
        int lx = lane % nx, rem = lane / nx;
        int ly = rem % ny, lz = rem / ny;
        int cid = (x0+lx) + GC*((y0+ly) + GC*(z0+lz));
        myStart = cs[cid];
        myCnt = cs[cid+1] - myStart;
    }
    int incl = myCnt;
    #pragma unroll
    for (int o = 1; o < 64; o <<= 1) {
        int v = __shfl_up(incl, o);
        if (lane >= o) incl += v;
    }
    const int total = __shfl(incl, 63);
    const int base = incl - myCnt;
    const bool ok = (total <= LCAP);
    if (ok) {
        for (int k2 = 0; k2 < myCnt; k2++) {
            int pos = myStart + k2;
            float4 cv = sp[pos];
            float dot = fmaf(qv.z, cv.z, fmaf(qv.y, cv.y, qv.x*cv.x));
            float d2 = fmaxf(fmaf(-2.f, dot, qv.w + cv.w), 0.f);
            lst[base+k2] = (((unsigned long long)__float_as_uint(d2)) << 32) | (unsigned)si[pos];
        }
        wave_top16(lst, total, o16, lane);
    }
    bool pass = false;
    if (ok && total >= KN) {
        float d2_16 = __uint_as_float((unsigned)(o16[KN-1] >> 32));
        float db = 1e30f;
        if (x0 > 0)     db = fminf(db, qv.x - (float)x0*GH);
        if (x1 < GC-1)  db = fminf(db, (float)(x1+1)*GH - qv.x);
        if (y0 > 0)     db = fminf(db, qv.y - (float)y0*GH);
        if (y1 < GC-1)  db = fminf(db, (float)(y1+1)*GH - qv.y);
        if (z0 > 0)     db = fminf(db, qv.z - (float)z0*GH);
        if (z1 < GC-1)  db = fminf(db, (float)(z1+1)*GH - qv.z);
        pass = (d2_16 + 1e-5f <= db*db);
    }
    if (!pass) {
        // exact chunked brute force over all candidates (rare)
        bool have = false;
        for (int c0 = 0; c0 < NN1; c0 += (LCAP - KN)) {
            int cn = min(NN1 - c0, LCAP - KN);
            for (int ii = lane; ii < cn; ii += 64) {
                int pos = c0 + ii;
                float4 cv = sp[pos];
                float dot = fmaf(qv.z, cv.z, fmaf(qv.y, cv.y, qv.x*cv.x));
                float d2 = fmaxf(fmaf(-2.f, dot, qv.w + cv.w), 0.f);
                lst[ii] = (((unsigned long long)__float_as_uint(d2)) << 32) | (unsigned)si[pos];
            }
            int tot2 = cn;
            if (have) {
                if (lane < KN) lst[cn + lane] = o16[lane];
                tot2 += KN;
            }
            wave_top16(lst, tot2, o16, lane);
            have = true;
        }
    }
    if (lane < KN)
        nidx[gp*KN + lane] = b*NN1 + (int)(o16[lane] & 0xffffffffull);
}

// ----------------------------- split-bf16 MFMA GEMM (near-fp32 via hi/lo x 3)
// mode 0: A plain. mode 2: A = concat(Amat, aux). mode 3: qkv, bf16 out —
//   seg0: q = xd@Wq ; seg1: e = xd - xi@Wk ; seg2: v2 = xi@Wv + xd.
template<int N, int K, int MODE, int STATS>
__global__ __launch_bounds__(256) void k_gemm_mf(
    const float* __restrict__ Amat, const unsigned short* __restrict__ Whi,
    const unsigned short* __restrict__ Wlo, const float* __restrict__ bias,
    float* __restrict__ C, const float* __restrict__ aux,
    float* __restrict__ sums, float* __restrict__ sumsq)
{
    __shared__ float sstat[STATS ? 2*N : 1];
    const int t = threadIdx.x, w = t >> 6, lane = t & 63;
    const int quad = lane >> 4, c = lane & 15;
    const int row = blockIdx.x*64 + w*16 + c;
    const int sA = (MODE == 2) ? DS : K;
    constexpr int nslab = K >> 5;
    constexpr int ncj = N >> 4;
    const int seg = (MODE == 3) ? blockIdx.y : 0;
    const float* Abase = (MODE == 3 && seg > 0) ? aux : Amat;
    const unsigned short* WhiS = Whi + (size_t)seg*32768;
    const unsigned short* WloS = Wlo + (size_t)seg*32768;
    float* CS = C + (size_t)seg*2097152;
    unsigned short* CS16 = (unsigned short*)C + (size_t)seg*4194304;
    if (STATS) {
        for (int i = t; i < 2*N; i += 256) sstat[i] = 0.f;
        __syncthreads();
    }
    floatx4 acc[ncj];
    #pragma unroll
    for (int cj = 0; cj < ncj; cj++) acc[cj] = (floatx4){0.f,0.f,0.f,0.f};

    #pragma unroll
    for (int slab = 0; slab < nslab; slab++) {
        const int kk = slab*32 + quad*8;
        const float* src;
        if (MODE == 2 && kk >= DS) src = aux + (size_t)row*DD + (kk - DS);
        else                       src = Abase + (size_t)row*sA + kk;
        floatx4 va = *(const floatx4*)src;
        floatx4 vb = *(const floatx4*)(src + 4);
        short8 ahi, alo;
        #pragma unroll
        for (int j = 0; j < 4; j++) {
            unsigned short h = f2bf(va[j]);
            ahi[j] = (short)h; alo[j] = (short)f2bf(va[j] - bf2f(h));
        }
        #pragma unroll
        for (int j = 0; j < 4; j++) {
            unsigned short h = f2bf(vb[j]);
            ahi[4+j] = (short)h; alo[4+j] = (short)f2bf(vb[j] - bf2f(h));
        }
        const short8* bh = (const short8*)WhiS + (size_t)slab*ncj*64;
        const short8* bl = (const short8*)WloS + (size_t)slab*ncj*64;
        #pragma unroll
        for (int cj = 0; cj < ncj; cj++) {
            short8 bhv = bh[cj*64 + lane];
            short8 blv = bl[cj*64 + lane];
            acc[cj] = __builtin_amdgcn_mfma_f32_16x16x32_bf16(alo, bhv, acc[cj], 0, 0, 0);
            acc[cj] = __builtin_amdgcn_mfma_f32_16x16x32_bf16(ahi, blv, acc[cj], 0, 0, 0);
            acc[cj] = __builtin_amdgcn_mfma_f32_16x16x32_bf16(ahi, bhv, acc[cj], 0, 0, 0);
        }
    }
    const int rbase = blockIdx.x*64 + w*16 + quad*4;
    #pragma unroll
    for (int cj = 0; cj < ncj; cj++) {
        const float bb = bias ? bias[cj*16 + c] : 0.f;
        float s = 0.f, ss = 0.f;
        #pragma unroll
        for (int p = 0; p < 4; p++) {
            float v = acc[cj][p] + bb;
            if (MODE == 3) {
                if (seg == 1) v = Amat[(size_t)(rbase + p)*DS + cj*16 + c] - v;  // e = xd - k
                if (seg == 2) v += Amat[(size_t)(rbase + p)*DS + cj*16 + c];     // v2 = v + xd
                CS16[(size_t)(rbase + p)*N + cj*16 + c] = f2bf(v);
            } else {
                CS[(size_t)(rbase + p)*N + cj*16 + c] = v;
            }
            if (STATS) { s += v; ss += v*v; }
        }
        if (STATS) {
            s  += __shfl_xor(s, 16);  s  += __shfl_xor(s, 32);
            ss += __shfl_xor(ss, 16); ss += __shfl_xor(ss, 32);
            if (quad == 0) {
                atomicAdd(&sstat[cj*16 + c], s);
                atomicAdd(&sstat[N + cj*16 + c], ss);
            }
        }
    }
    if (STATS) {
        __syncthreads();
        for (int i = t; i < N; i += 256) {
            atomicAdd(&sums[i],  sstat[i]);
            atomicAdd(&sumsq[i], sstat[N + i]);
        }
    }
}

// ------------------------------------------- MFMA h-GEMM + fused BN stats
// h row r = q[r>>4] + e[nidx[r]]  (q, e in bf16)
__global__ __launch_bounds__(256) void k_gemm_h(
    const unsigned short* __restrict__ q, const unsigned short* __restrict__ e,
    const int* __restrict__ nidx,
    const unsigned short* __restrict__ W1sw, const float* __restrict__ b1,
    unsigned short* __restrict__ hpre,
    float* __restrict__ sums, float* __restrict__ sumsq)
{
    __shared__ unsigned short WF[16384];
    __shared__ unsigned short outT[128*128];
    __shared__ float sstat[256];
    const int t = threadIdx.x;
    const int w = t >> 6, lane = t & 63;
    sstat[t] = 0.f;
    #pragma unroll
    for (int i = 0; i < 8; i++)
        ((uint4*)WF)[t + 256*i] = ((const uint4*)W1sw)[t + 256*i];
    __syncthreads();

    const int quad = lane >> 4, c = lane & 15;
    const int r0 = blockIdx.x * 128 + w * 32;
    const int nid0 = nidx[r0 + c];
    const int nid1 = nidx[r0 + 16 + c];
    const int pr0 = r0 >> 4;
    const int pr1 = pr0 + 1;

    floatx4 acc[2][8];
    #pragma unroll
    for (int ti = 0; ti < 2; ti++)
        #pragma unroll
        for (int cj = 0; cj < 8; cj++)
            acc[ti][cj] = (floatx4){0.f, 0.f, 0.f, 0.f};

    for (int ks = 0; ks < 4; ks++) {
        short8 bf[8];
        #pragma unroll
        for (int cj = 0; cj < 8; cj++)
            bf[cj] = ((const short8*)WF)[(ks*8 + cj)*64 + lane];
        const int ko = ks*32 + quad*8;
        #pragma unroll
        for (int ti = 0; ti < 2; ti++) {
            const int pr = ti ? pr1 : pr0;
            const int m  = ti ? nid1 : nid0;
            uint4 qv = *(const uint4*)(q + (size_t)pr*DS + ko);
            uint4 ev = *(const uint4*)(e + (size_t)m*DS + ko);
            unsigned qw[4] = {qv.x, qv.y, qv.z, qv.w};
            unsigned ew[4] = {ev.x, ev.y, ev.z, ev.w};
            short8 af;
            #pragma unroll
            for (int j = 0; j < 4; j++) {
                float f0 = bf2f((unsigned short)(qw[j] & 0xffffu))
                         + bf2f((unsigned short)(ew[j] & 0xffffu));
                float f1 = bf2f((unsigned short)(qw[j] >> 16))
                         + bf2f((unsigned short)(ew[j] >> 16));
                af[2*j]   = (short)f2bf(f0);
                af[2*j+1] = (short)f2bf(f1);
            }
            #pragma unroll
            for (int cj = 0; cj < 8; cj++)
                acc[ti][cj] = __builtin_amdgcn_mfma_f32_16x16x32_bf16(af, bf[cj], acc[ti][cj], 0, 0, 0);
        }
    }

    #pragma unroll
    for (int cj = 0; cj < 8; cj++) {
        const float bb = b1[cj*16 + c];
        float s = 0.f, ss = 0.f;
        #pragma unroll
        for (int ti = 0; ti < 2; ti++)
            #pragma unroll
            for (int p = 0; p < 4; p++) {
                float v = acc[ti][cj][p] + bb;
                s += v; ss += v*v;
                int lr = w*32 + ti*16 + quad*4 + p;
                outT[lr*128 + cj*16 + c] = f2bf(v);
            }
        s  += __shfl_xor(s, 16);  s  += __shfl_xor(s, 32);
        ss += __shfl_xor(ss, 16); ss += __shfl_xor(ss, 32);
        if (quad == 0) {
            atomicAdd(&sstat[cj*16 + c], s);
            atomicAdd(&sstat[128 + cj*16 + c], ss);
        }
    }
    __syncthreads();
    unsigned short* gdst = hpre + (size_t)blockIdx.x * 128 * 128;
    #pragma unroll
    for (int i = 0; i < 8; i++)
        ((uint4*)gdst)[t + 256*i] = ((const uint4*)outT)[t + 256*i];
    if (t < 128) atomicAdd(&sums[t], sstat[t]);
    else         atomicAdd(&sumsq[t - 128], sstat[t]);
}

// --------- MFMA attn: inline BN finalize -> bn+relu -> sim -> softmax -> agg
__global__ __launch_bounds__(256) void k_attn2(
    const unsigned short* __restrict__ hpre, const float* __restrict__ sums_h,
    const float* __restrict__ sumsq_h, const float* __restrict__ g1,
    const float* __restrict__ bt1, const unsigned short* __restrict__ W2sw,
    const unsigned short* __restrict__ v, const int* __restrict__ nidx,
    float* __restrict__ agg)
{
    __shared__ unsigned short WF[16384];
    __shared__ float s_sc[DS], s_sh[DS];
    const int t = threadIdx.x;
    #pragma unroll
    for (int i = 0; i < 8; i++)
        ((uint4*)WF)[t + 256*i] = ((const uint4*)W2sw)[t + 256*i];
    if (t < DS) {
        const float invM = 1.f / (float)MH;
        float m   = sums_h[t] * invM;
        float var = sumsq_h[t] * invM - m*m;
        float sc  = g1[t] * rsqrtf(var + 1e-5f);
        s_sc[t] = sc;
        s_sh[t] = bt1[t] - m * sc;
    }
    __syncthreads();

    const int w = t >> 6, lane = t & 63;
    const int gp = blockIdx.x * 4 + w;
    const int quad = lane >> 4, c = lane & 15;

    floatx4 acc[8];
    #pragma unroll
    for (int cj = 0; cj < 8; cj++) acc[cj] = (floatx4){0.f, 0.f, 0.f, 0.f};

    for (int ks = 0; ks < 4; ks++) {
        const int ko = ks*32 + quad*8;
        const unsigned short* hp = hpre + ((size_t)gp*16 + c)*DS + ko;
        uint4 hv = *(const uint4*)hp;
        floatx4 sc0 = *(const floatx4*)&s_sc[ko];
        floatx4 sc1 = *(const floatx4*)&s_sc[ko + 4];
        floatx4 sh0 = *(const floatx4*)&s_sh[ko];
        floatx4 sh1 = *(const floatx4*)&s_sh[ko + 4];
        unsigned int hw[4] = {hv.x, hv.y, hv.z, hv.w};
        short8 af;
        #pragma unroll
        for (int j = 0; j < 4; j++) {
            unsigned short u0 = (unsigned short)(hw[j] & 0xffffu);
            unsigned short u1 = (unsigned short)(hw[j] >> 16);
            float f0 = fmaxf(fmaf(bf2f(u0), (j<2)?sc0[2*j]:sc1[2*j-4],   (j<2)?sh0[2*j]:sh1[2*j-4]),   0.f);
            float f1 = fmaxf(fmaf(bf2f(u1), (j<2)?sc0[2*j+1]:sc1[2*j-3], (j<2)?sh0[2*j+1]:sh1[2*j-3]), 0.f);
            af[2*j]   = (short)f2bf(f0);
            af[2*j+1] = (short)f2bf(f1);
        }
        #pragma unroll
        for (int cj = 0; cj < 8; cj++) {
            short8 bfv = ((const short8*)WF)[(ks*8 + cj)*64 + lane];
            acc[cj] = __builtin_amdgcn_mfma_f32_16x16x32_bf16(af, bfv, acc[cj], 0, 0, 0);
        }
    }

    int nid[4];
    #pragma unroll
    for (int p = 0; p < 4; p++) nid[p] = nidx[gp*16 + quad*4 + p];

    #pragma unroll
    for (int cj = 0; cj < 8; cj++) {
        float m4 = fmaxf(fmaxf(acc[cj][0], acc[cj][1]), fmaxf(acc[cj][2], acc[cj][3]));
        m4 = fmaxf(m4, __shfl_xor(m4, 16));
        m4 = fmaxf(m4, __shfl_xor(m4, 32));
        float e[4]; float s4 = 0.f;
        #pragma unroll
        for (int p = 0; p < 4; p++) { e[p] = __expf(acc[cj][p] - m4); s4 += e[p]; }
        s4 += __shfl_xor(s4, 16); s4 += __shfl_xor(s4, 32);
        const float inv = 1.f / s4;
        const int col = cj*16 + c;
        float a = 0.f;
        #pragma unroll
        for (int p = 0; p < 4; p++)
            a = fmaf(e[p]*inv, bf2f(v[(size_t)nid[p]*DS + col]), a);
        a += __shfl_xor(a, 16); a += __shfl_xor(a, 32);
        if (quad == 0) agg[(size_t)gp*DS + col] = a;
    }
}

// bn+relu, float4-vectorized, inline finalize (memory-bound)
__global__ __launch_bounds__(256) void k_bnrelu(
    const float4* __restrict__ X, const float* __restrict__ sums,
    const float* __restrict__ sumsq, const float* __restrict__ g,
    const float* __restrict__ bt, float invM,
    float4* __restrict__ Y, size_t total4, int N)
{
    size_t i = (size_t)blockIdx.x * 256 + threadIdx.x;
    if (i < total4) {
        int c = (int)((i*4) & (size_t)(N - 1));
        float4 sm = *(const float4*)(sums + c);
        float4 sq = *(const float4*)(sumsq + c);
        float4 gg = *(const float4*)(g + c);
        float4 bb = *(const float4*)(bt + c);
        float4 x = X[i], y;
        float m0 = sm.x*invM, m1 = sm.y*invM, m2 = sm.z*invM, m3 = sm.w*invM;
        float s0 = gg.x*rsqrtf(sq.x*invM - m0*m0 + 1e-5f);
        float s1 = gg.y*rsqrtf(sq.y*invM - m1*m1 + 1e-5f);
        float s2 = gg.z*rsqrtf(sq.z*invM - m2*m2 + 1e-5f);
        float s3 = gg.w*rsqrtf(sq.w*invM - m3*m3 + 1e-5f);
        y.x = fmaxf(fmaf(x.x, s0, bb.x - m0*s0), 0.f);
        y.y = fmaxf(fmaf(x.y, s1, bb.y - m1*s1), 0.f);
        y.z = fmaxf(fmaf(x.z, s2, bb.z - m2*s2), 0.f);
        y.w = fmaxf(fmaf(x.w, s3, bb.w - m3*s3), 0.f);
        Y[i] = y;
    }
}

// ------- cooperative radix-select top-K, 2 queries/block (interp only)
template<int NCAND, int KSEL, int EPI>
__global__ __launch_bounds__(256) void k_sel(
    const float4* __restrict__ qpts4, const float4* __restrict__ cpts4,
    int* __restrict__ nidx, const float* __restrict__ x2, float* __restrict__ xi)
{
    __shared__ unsigned hist0[1024], hist1[1024];
    __shared__ unsigned skey[2][64];
    __shared__ unsigned sidx[2][64];
    __shared__ float    swtE[2][KSEL];
    __shared__ unsigned sidxE[2][KSEL];
    __shared__ unsigned wpart[2][4];
    __shared__ int      sstate[20];

    const int gp0 = blockIdx.x * 2;
    const int b = gp0 >> 12;
    const int t = threadIdx.x, wv = t >> 6, lane = t & 63;
    constexpr int ITER = NCAND / 256;

    const float4 qv0 = qpts4[gp0];
    const float4 qv1 = qpts4[gp0 + 1];
    const float4* pb = cpts4 + (size_t)b*NCAND;

    unsigned kreg[2][ITER];
    ((uint4*)hist0)[t] = (uint4){0u,0u,0u,0u};
    ((uint4*)hist1)[t] = (uint4){0u,0u,0u,0u};
    __syncthreads();
    #pragma unroll
    for (int it = 0; it < ITER; it++) {
        int j = t + 256*it;
        float4 cv = pb[j];
        float dot0 = fmaf(qv0.z, cv.z, fmaf(qv0.y, cv.y, qv0.x*cv.x));
        float dot1 = fmaf(qv1.z, cv.z, fmaf(qv1.y, cv.y, qv1.x*cv.x));
        float d20 = fmaxf(fmaf(-2.f, dot0, qv0.w + cv.w), 0.f);
        float d21 = fmaxf(fmaf(-2.f, dot1, qv1.w + cv.w), 0.f);
        unsigned k0 = (unsigned)(d20 * KSCALE);
        unsigned k1 = (unsigned)(d21 * KSCALE);
        kreg[0][it] = k0; kreg[1][it] = k1;
        atomicAdd(&hist0[k0 >> 20], 1u);
        atomicAdd(&hist1[k1 >> 20], 1u);
    }
    __syncthreads();

    uint4 h40 = ((const uint4*)hist0)[t];
    uint4 h41 = ((const uint4*)hist1)[t];
    unsigned hv0[4] = {h40.x, h40.y, h40.z, h40.w};
    unsigned hv1[4] = {h41.x, h41.y, h41.z, h41.w};
    unsigned tsum0 = hv0[0]+hv0[1]+hv0[2]+hv0[3];
    unsigned tsum1 = hv1[0]+hv1[1]+hv1[2]+hv1[3];
    unsigned incl0 = tsum0, incl1 = tsum1;
    #pragma unroll
    for (int off = 1; off < 64; off <<= 1) {
        unsigned o0 = (unsigned)__shfl_up((int)incl0, off);
        unsigned o1 = (unsigned)__shfl_up((int)incl1, off);
        if (lane >= off) { incl0 += o0; incl1 += o1; }
    }
    if (lane == 63) { wpart[0][wv] = incl0; wpart[1][wv] = incl1; }
    __syncthreads();
    unsigned wbase0 = 0, wbase1 = 0;
    for (int i2 = 0; i2 < wv; i2++) { wbase0 += wpart[0][i2]; wbase1 += wpart[1][i2]; }
    const unsigned excl0 = wbase0 + incl0 - tsum0;
    const unsigned excl1 = wbase1 + incl1 - tsum1;
    if ((int)excl0 < KSEL && KSEL <= (int)(excl0 + tsum0)) {
        unsigned cum = excl0;
        #pragma unroll
        for (int i2 = 0; i2 < 4; i2++) {
            unsigned h = hv0[i2];
            if ((int)cum < KSEL && KSEL <= (int)(cum + h)) {
                sstate[0] = t*4 + i2; sstate[1] = (int)cum; sstate[2] = (int)h;
                sstate[3] = ((int)cum + (int)h <= 64) ? 1 : 0; sstate[4] = 0;
                break;
            }
            cum += h;
        }
    }
    if ((int)excl1 < KSEL && KSEL <= (int)(excl1 + tsum1)) {
        unsigned cum = excl1;
        #pragma unroll
        for (int i2 = 0; i2 < 4; i2++) {
            unsigned h = hv1[i2];
            if ((int)cum < KSEL && KSEL <= (int)(cum + h)) {
                sstate[8] = t*4 + i2; sstate[9] = (int)cum; sstate[10] = (int)h;
                sstate[11] = ((int)cum + (int)h <= 64) ? 1 : 0; sstate[12] = 0;
                break;
            }
            cum += h;
        }
    }
    __syncthreads();

    if (sstate[3] == 1 && sstate[11] == 1) {
        const unsigned P0 = (unsigned)sstate[0];
        const unsigned P1 = (unsigned)sstate[8];
        const unsigned long long lmask = (1ull << lane) - 1ull;
        #pragma unroll
        for (int it = 0; it < ITER; it++) {
            int j = t + 256*it;
            unsigned k0 = kreg[0][it], k1 = kreg[1][it];
            bool f0 = ((k0 >> 20) <= P0);
            bool f1 = ((k1 >> 20) <= P1);
            unsigned long long bal0 = __ballot(f0);
            unsigned long long bal1 = __ballot(f1);
            int w0 = __popcll(bal0), w1 = __popcll(bal1);
            int b0 = 0, b1 = 0;
            if (lane == 0 && w0) b0 = atomicAdd((unsigned*)&sstate[4], (unsigned)w0);
            if (lane == 0 && w1) b1 = atomicAdd((unsigned*)&sstate[12], (unsigned)w1);
            b0 = __shfl(b0, 0); b1 = __shfl(b1, 0);
            if (f0) { int pos = b0 + __popcll(bal0 & lmask); skey[0][pos] = k0; sidx[0][pos] = (unsigned)j; }
            if (f1) { int pos = b1 + __popcll(bal1 & lmask); skey[1][pos] = k1; sidx[1][pos] = (unsigned)j; }
        }
    } else {
        #pragma unroll
        for (int qi = 0; qi < 2; qi++) {
            const float4 qv = qi ? qv1 : qv0;
            unsigned P = (unsigned)sstate[qi*8+0];
            int S = sstate[qi*8+1], cntB = sstate[qi*8+2], mode = sstate[qi*8+3];
            int gsh = 20;
            if (mode == 0) {
                for (int round = 1; round < 4; round++) {
                    const int nb  = (round == 3) ? 16 : 256;
                    const int wb  = (round == 3) ? 4 : 8;
                    const int sh  = (round == 1) ? 12 : (round == 2 ? 4 : 0);
                    const int psh = sh + wb;
                    if (t < nb) hist0[t] = 0u;
                    __syncthreads();
                    #pragma unroll
                    for (int it = 0; it < ITER; it++) {
                        unsigned key = kreg[qi][it];
                        if ((key >> psh) == P)
                            atomicAdd(&hist0[(key >> sh) & (nb - 1)], 1u);
                    }
                    __syncthreads();
                    unsigned hv = (t < nb) ? hist0[t] : 0u;
                    unsigned tsum = hv;
                    unsigned incl = tsum;
                    #pragma unroll
                    for (int off = 1; off < 64; off <<= 1) {
                        unsigned o = (unsigned)__shfl_up((int)incl, off);
                        if (lane >= off) incl += o;
                    }
                    if (lane == 63) wpart[0][wv] = incl;
                    __syncthreads();
                    unsigned wbase = 0;
                    for (int i2 = 0; i2 < wv; i2++) wbase += wpart[0][i2];
                    unsigned exclT = wbase + incl - tsum;
                    const int need = KSEL - S;
                    if ((int)exclT < need && need <= (int)(exclT + tsum)) {
                        int Snew = S + (int)exclT;
                        int tot  = Snew + (int)tsum;
                        sstate[qi*8+0] = (int)((P << wb) | (unsigned)t);
                        sstate[qi*8+1] = Snew; sstate[qi*8+2] = (int)tsum;
                        sstate[qi*8+3] = (tot <= 64) ? 1 : ((round == 3) ? 2 : 0);
                        sstate[qi*8+4] = 0;
                    }
                    __syncthreads();
                    P = (unsigned)sstate[qi*8+0]; S = sstate[qi*8+1];
                    cntB = sstate[qi*8+2]; mode = sstate[qi*8+3];
                    gsh = sh;
                    if (mode) break;
                }
            }
            if (mode == 1) {
                const unsigned long long lmask = (1ull << lane) - 1ull;
                #pragma unroll
                for (int it = 0; it < ITER; it++) {
                    int j = t + 256*it;
                    unsigned key = kreg[qi][it];
                    bool f = ((key >> gsh) <= P);
                    unsigned long long bal = __ballot(f);
                    int wcnt = __popcll(bal);
                    int base = 0;
                    if (lane == 0 && wcnt) base = atomicAdd((unsigned*)&sstate[qi*8+4], (unsigned)wcnt);
                    base = __shfl(base, 0);
                    if (f) {
                        int pos = base + __popcll(bal & lmask);
                        skey[qi][pos] = key; sidx[qi][pos] = (unsigned)j;
                    }
                }
            } else {
                if (t < 64) {
                    const unsigned long long lmask = (1ull << lane) - 1ull;
                    int cnt = 0;
                    for (int pass = 0; pass < 2; pass++) {
                        for (int it = 0; it < NCAND/64; it++) {
                            int j = lane + 64*it;
                            float4 cv = pb[j];
                            float dot = fmaf(qv.z, cv.z, fmaf(qv.y, cv.y, qv.x*cv.x));
                            float d2 = fmaxf(fmaf(-2.f, dot, qv.w + cv.w), 0.f);
                            unsigned key = (unsigned)(d2 * KSCALE);
                            bool f = pass ? (key == P) : (key < P);
                            unsigned long long bal = __ballot(f);
                            if (f) {
                                int pos = cnt + __popcll(bal & lmask);
                                if (pos < 64) { skey[qi][pos] = key; sidx[qi][pos] = (unsigned)j; }
                            }
                            cnt += __popcll(bal);
                        }
                    }
                    if (lane == 0) { sstate[qi*8+1] = min(cnt, 64); sstate[qi*8+2] = 0; }
                }
            }
            __syncthreads();
        }
    }
    __syncthreads();

    if (wv < 2) {
        const int q = wv;
        const int total = sstate[q*8+1] + sstate[q*8+2];
        unsigned long long v = ~0ull;
        if (lane < total)
            v = (((unsigned long long)skey[q][lane]) << 32) | sidx[q][lane];
        #pragma unroll
        for (int k = 2; k <= 64; k <<= 1) {
            #pragma unroll
            for (int jj = k >> 1; jj > 0; jj >>= 1) {
                unsigned long long p = shfl_xor_u64(v, jj);
                bool up = ((lane & k) == 0);
                bool takeMin = (((lane & jj) == 0) == up);
                bool pl = p < v;
                v = (takeMin == pl) ? p : v;
            }
        }
        if (EPI == 0) {
            if (lane < KSEL)
                nidx[(gp0 + q)*KSEL + lane] = b*NCAND + (int)(v & 0xffffffffull);
        } else {
            const float4 qq = q ? qv1 : qv0;
            float wgt = 0.f;
            unsigned si = (unsigned)(v & 0xffffffffull);
            if (lane < KSEL) {
                float4 cv = pb[si];
                float dot = fmaf(qq.z, cv.z, fmaf(qq.y, cv.y, qq.x*cv.x));
                float d2 = fmaxf(fmaf(-2.f, dot, qq.w + cv.w), 0.f);
                wgt = 1.f / (sqrtf(d2) + 1e-8f);
            }
            float ws = wgt;
            ws += __shfl_xor(ws, 1); ws += __shfl_xor(ws, 2); ws += __shfl_xor(ws, 4);
            if (lane < KSEL) {
                swtE[q][lane]  = wgt / ws;
                sidxE[q][lane] = si;
            }
        }
    }

    if (EPI == 1) {
        __syncthreads();
        const int qi2 = t >> 7, tt = t & 127;
        const float* x2b = x2 + (size_t)b*NCAND*DS;
        float a = 0.f;
        #pragma unroll
        for (int r = 0; r < KSEL; r++)
            a = fmaf(swtE[qi2][r], x2b[(size_t)sidxE[qi2][r]*DS + tt], a);
        xi[(size_t)(gp0 + qi2)*DS + tt] = a;
    }
}

// ---------------------------------------------------------------- launch
extern "C" void kernel_launch(void* const* d_in, const int* in_sizes, int n_in,
                              void* d_out, int out_size, void* d_ws, size_t ws_size,
                              hipStream_t stream)
{
    const float* p1 = (const float*)d_in[0];
    const float* x1 = (const float*)d_in[1];
    const int*   o1 = (const int*)d_in[2];
    const float* p2 = (const float*)d_in[3];
    const float* x2 = (const float*)d_in[4];
    const float* W_dense = (const float*)d_in[7];
    const float* b_dense = (const float*)d_in[8];
    const float* g_dense = (const float*)d_in[9];
    const float* bt_dense= (const float*)d_in[10];
    const float* Wq = (const float*)d_in[11];
    const float* Wk = (const float*)d_in[12];
    const float* Wv = (const float*)d_in[13];
    const float* W1 = (const float*)d_in[14];
    const float* b1 = (const float*)d_in[15];
    const float* g1 = (const float*)d_in[16];
    const float* bt1= (const float*)d_in[17];
    const float* W2 = (const float*)d_in[18];
    const float* W_out = (const float*)d_in[20];
    const float* b_out = (const float*)d_in[21];
    const float* g_out = (const float*)d_in[22];
    const float* bt_out= (const float*)d_in[23];

    float* ws   = (float*)d_ws;
    unsigned short* hpre = (unsigned short*)(ws + OFF_HPRE);
    unsigned short* wts  = (unsigned short*)(ws + OFF_WTS);
    float* tmp  = ws + OFF_TMP;
    float* xd   = ws + OFF_XD;
    float* xi   = ws + OFF_XI;
    float* qm   = ws + OFF_Q;
    float* outp = ws + OFF_OUTP;
    int*   nidx = (int*)(ws + OFF_NIDX);
    float* stat = ws + OFF_STAT;
    float4* p1q = (float4*)(ws + OFF_P1Q);
    float4* p2q = (float4*)(ws + OFF_P2Q);
    float4* spts = (float4*)(ws + OFF_SPTS);
    int*   sidxA = (int*)(ws + OFF_SIDX);
    int*   cstA  = (int*)(ws + OFF_CST);
    unsigned short* q16 = (unsigned short*)(ws + OFF_Q);
    unsigned short* e16 = (unsigned short*)(ws + OFF_K);
    unsigned short* v16 = (unsigned short*)(ws + OFF_V);
    float* sums_d = stat,      *sumsq_d = stat+256;
    float* sums_h = stat+1024, *sumsq_h = stat+1280;
    float* sums_o = stat+2048, *sumsq_o = stat+2304;
    float* out = (float*)d_out;

    // prolog + weight swizzles, one launch
    SwzParams sp;
    sp.W[0]=W_dense; sp.W[1]=Wq; sp.W[2]=Wk; sp.W[3]=Wv; sp.W[4]=W1; sp.W[5]=W2; sp.W[6]=W_out;
    sp.hi[0]=wts+WDH; sp.hi[1]=wts+WQH; sp.hi[2]=wts+WKH; sp.hi[3]=wts+WVH;
    sp.hi[4]=wts+W1H; sp.hi[5]=wts+W2H; sp.hi[6]=wts+WOH;
    sp.lo[0]=wts+WDL; sp.lo[1]=wts+WQL; sp.lo[2]=wts+WKL; sp.lo[3]=wts+WVL;
    sp.lo[4]=wts+W1L; sp.lo[5]=wts+W2L; sp.lo[6]=wts+WOL;
    sp.N[0]=128; sp.N[1]=128; sp.N[2]=128; sp.N[3]=128; sp.N[4]=128; sp.N[5]=128; sp.N[6]=256;
    sp.fid0[0]=0; sp.fid0[1]=16; sp.fid0[2]=48; sp.fid0[3]=80; sp.fid0[4]=112;
    sp.fid0[5]=144; sp.fid0[6]=176; sp.fid0[7]=272;
    k_prolog<<<NPRO + 68, 256, 0, stream>>>(p1, o1, p2, out, stat, p1q, p2q, sp);

    // grid binning for kNN
    k_bin<<<BB, 256, 0, stream>>>(p1, spts, sidxA, cstA);

    // dense_mlp (stats fused) -> bn+relu (finalize inline, float4)
    k_gemm_mf<128,64,0,1><<<M1/64, 256, 0, stream>>>(x1, wts+WDH, wts+WDL, b_dense, tmp,
        nullptr, sums_d, sumsq_d);
    k_bnrelu<<<(M1*DS/4)/256, 256, 0, stream>>>((const float4*)tmp, sums_d, sumsq_d,
        g_dense, bt_dense, 1.f/(float)M1, (float4*)xd, (size_t)M1*DS/4, DS);

    // interpolation (2 queries/block radix select, K=8)
    k_sel<NN2, KI, 1><<<M1/2, 256, 0, stream>>>(p1q, p2q, nullptr, x2, xi);

    // q, k, v projections — one launch; bf16 outputs: q / e=xd-k / v2=v+xd
    k_gemm_mf<128,128,3,0><<<dim3(M1/64,3), 256, 0, stream>>>(xd, wts+WQH, wts+WQL,
        nullptr, qm, xi, nullptr, nullptr);

    // kNN-16: grid-accelerated exact search, 1 wave per query
    k_knn_grid<<<M1/4, 256, 0, stream>>>(p1q, spts, sidxA, cstA, nidx);

    // h-GEMM (MFMA, fused BN stats, bf16 q+e streams) -> hpre bf16
    k_gemm_h<<<MH/128, 256, 0, stream>>>(q16, e16, nidx, wts+W1H, b1, hpre, sums_h, sumsq_h);

    // attn (MFMA, BN finalize inline, bf16 v2)
    k_attn2<<<M1/4, 256, 0, stream>>>(hpre, sums_h, sumsq_h, g1, bt1, wts+W2H, v16, nidx, tmp);

    // output mlp (stats fused) -> bn+relu (finalize inline, float4)
    k_gemm_mf<256,192,2,1><<<M1/64, 256, 0, stream>>>(tmp, wts+WOH, wts+WOL, b_out, outp,
        x1, sums_o, sumsq_o);
    k_bnrelu<<<(M1*DOUT/4)/256, 256, 0, stream>>>((const float4*)outp, sums_o, sumsq_o,
        g_out, bt_out, 1.f/(float)M1, (float4*)(out + OUT_X), (size_t)M1*DOUT/4, DOUT);
}

// Round 15
// 380.381 us; speedup vs baseline: 1.2242x; 1.2242x over previous
//
#include <hip/hip_runtime.h>
#include <math.h>

#define BB 4
#define NN1 4096
#define NN2 1024
#define DS 128
#define DD 64
#define DOUT 256
#define M1 16384        // BB*NN1
#define MH 262144       // M1*16
#define KCAT 192        // DS+DD
#define KI 8            // interp k
#define KN 16           // neighbor k

#define OUT_P1 49152
#define OUT_X  49152
#define OUT_O1 4243456

#define KSCALE 268435456.f   // 2^28: fixed-point key scale for d^2 (<4)

// ---- workspace layout (float offsets) ----
static const size_t OFF_HPRE = 0;                      // bf16 MH*DS
static const size_t OFF_WTS  = 16777216;               // swizzled weights (hi/lo)
static const size_t OFF_TMP  = 33554432;
static const size_t OFF_XD   = OFF_TMP  + 2097152;     // (unused now)
static const size_t OFF_XI   = OFF_XD   + 2097152;
static const size_t OFF_Q    = OFF_XI   + 2097152;     // bf16 q
static const size_t OFF_K    = OFF_Q    + 2097152;     // bf16 e = xd - k
static const size_t OFF_V    = OFF_K    + 2097152;     // bf16 v2 = v + xd
static const size_t OFF_OUTP = OFF_V    + 2097152;
static const size_t OFF_NIDX = OFF_OUTP + 4194304;
static const size_t OFF_STAT = OFF_NIDX + 262144;      // 3072 floats
static const size_t OFF_P1Q  = OFF_STAT + 4096;        // 16384 float4
static const size_t OFF_P2Q  = OFF_P1Q  + 65536;       // 4096 float4

// ushort offsets inside the weights region
#define WDH 0
#define WDL 8192
#define WQH 16384
#define WQL 32768
#define WKH 49152
#define WKL 65536
#define WVH 81920
#define WVL 98304
#define W1H 114688
#define W1L 131072
#define W2H 147456
#define W2L 163840
#define WOH 180224
#define WOL 229376

typedef __attribute__((ext_vector_type(8))) short short8;
typedef __attribute__((ext_vector_type(4))) float floatx4;

__device__ inline unsigned short f2bf(float f) {
    union { float f; unsigned int u; } x; x.f = f;
    unsigned int r = x.u + 0x7fffu + ((x.u >> 16) & 1u);
    return (unsigned short)(r >> 16);
}
__device__ inline float bf2f(unsigned short h) {
    union { unsigned int u; float f; } x; x.u = ((unsigned int)h) << 16;
    return x.f;
}
__device__ inline unsigned long long shfl_xor_u64(unsigned long long v, int m) {
    unsigned lo = (unsigned)v, hi = (unsigned)(v >> 32);
    lo = (unsigned)__shfl_xor((int)lo, m);
    hi = (unsigned)__shfl_xor((int)hi, m);
    return ((unsigned long long)hi << 32) | lo;
}

// --------- prolog + swizzle merged: copyout, stat zero, point pack, W swizzle
#define PRO_STAT  (OUT_P1 + BB)          // 49156
#define PRO_PACK  (PRO_STAT + 3072)      // 52228
#define PRO_TOTAL (PRO_PACK + M1 + BB*NN2)   // 72708
#define NPRO 285
struct SwzParams {
    const float* W[7];
    unsigned short* hi[7];
    unsigned short* lo[7];
    int N[7];
    int fid0[8];
};
__global__ __launch_bounds__(256) void k_prolog(
    const float* __restrict__ p1, const int* __restrict__ o1,
    const float* __restrict__ p2, float* __restrict__ out,
    float* __restrict__ stat, float4* __restrict__ p1q,
    float4* __restrict__ p2q, SwzParams p)
{
    if (blockIdx.x < NPRO) {
        int i = blockIdx.x * 256 + threadIdx.x;
        if (i < OUT_P1) out[i] = p1[i];
        else if (i < PRO_STAT) out[OUT_O1 + (i - OUT_P1)] = (float)o1[i - OUT_P1];
        else if (i < PRO_PACK) stat[i - PRO_STAT] = 0.f;
        else if (i < PRO_TOTAL) {
            int j = i - PRO_PACK;
            const float* src; float4* dst; int jj;
            if (j < M1) { src = p1; dst = p1q; jj = j; }
            else        { src = p2; dst = p2q; jj = j - M1; }
            float x = src[jj*3+0], y = src[jj*3+1], z = src[jj*3+2];
            float n = fmaf(z, z, fmaf(y, y, x*x));
            dst[jj] = make_float4(x, y, z, n);
        }
        return;
    }
    int fid = (blockIdx.x - NPRO)*4 + (threadIdx.x >> 6);
    int lane = threadIdx.x & 63;
    if (fid >= 272) return;
    int seg = 0;
    #pragma unroll
    for (int i = 1; i < 7; i++) if (fid >= p.fid0[i]) seg = i;
    int f = fid - p.fid0[seg];
    const float* W = p.W[seg];
    int N = p.N[seg];
    int ncj = N >> 4;
    int slab = f / ncj, cj = f - slab*ncj;
    int n  = cj*16 + (lane & 15);
    int k0 = slab*32 + (lane >> 4)*8;
    unsigned int oh[8], ol[8];
    #pragma unroll
    for (int j = 0; j < 8; j++) {
        float v = W[(size_t)(k0 + j) * N + n];
        unsigned short h = f2bf(v);
        oh[j] = h;
        ol[j] = f2bf(v - bf2f(h));
    }
    uint4 ph, pl;
    ph.x = oh[0] | (oh[1] << 16); ph.y = oh[2] | (oh[3] << 16);
    ph.z = oh[4] | (oh[5] << 16); ph.w = oh[6] | (oh[7] << 16);
    pl.x = ol[0] | (ol[1] << 16); pl.y = ol[2] | (ol[3] << 16);
    pl.z = ol[4] | (ol[5] << 16); pl.w = ol[6] | (ol[7] << 16);
    ((uint4*)p.hi[seg])[f*64 + lane] = ph;
    ((uint4*)p.lo[seg])[f*64 + lane] = pl;
}

// ----------------------------- split-bf16 MFMA GEMM (near-fp32 via hi/lo x 3)
// mode 0: A plain. mode 2: A = concat(Amat, aux). mode 3: qkv, bf16 out —
//   seg0: q = bn(tmp)@Wq ; seg1: e = bn(tmp) - xi@Wk ; seg2: v2 = xi@Wv + bn(tmp).
// BNA: apply relu(x*sc+sh) (dense BN, stats in bsums/bsumsq) to Amat reads.
template<int N, int K, int MODE, int STATS, int BNA>
__global__ __launch_bounds__(256) void k_gemm_mf(
    const float* __restrict__ Amat, const unsigned short* __restrict__ Whi,
    const unsigned short* __restrict__ Wlo, const float* __restrict__ bias,
    float* __restrict__ C, const float* __restrict__ aux,
    float* __restrict__ sums, float* __restrict__ sumsq,
    const float* __restrict__ bsums, const float* __restrict__ bsumsq,
    const float* __restrict__ bg, const float* __restrict__ bbt)
{
    __shared__ float sstat[STATS ? 2*N : 1];
    __shared__ float sbn[BNA ? 2*DS : 1];
    const int t = threadIdx.x, w = t >> 6, lane = t & 63;
    const int quad = lane >> 4, c = lane & 15;
    const int row = blockIdx.x*64 + w*16 + c;
    const int sA = (MODE == 2) ? DS : K;
    constexpr int nslab = K >> 5;
    constexpr int ncj = N >> 4;
    const int seg = (MODE == 3) ? blockIdx.y : 0;
    const float* Abase = (MODE == 3 && seg > 0) ? aux : Amat;
    const unsigned short* WhiS = Whi + (size_t)seg*32768;
    const unsigned short* WloS = Wlo + (size_t)seg*32768;
    float* CS = C + (size_t)seg*2097152;
    unsigned short* CS16 = (unsigned short*)C + (size_t)seg*4194304;
    if (STATS) {
        for (int i = t; i < 2*N; i += 256) sstat[i] = 0.f;
    }
    if (BNA) {
        if (t < DS) {
            const float invM = 1.f / (float)M1;
            float m   = bsums[t] * invM;
            float var = bsumsq[t] * invM - m*m;
            float sc  = bg[t] * rsqrtf(var + 1e-5f);
            sbn[t] = sc;
            sbn[DS + t] = bbt[t] - m * sc;
        }
    }
    if (STATS || BNA) __syncthreads();

    floatx4 acc[ncj];
    #pragma unroll
    for (int cj = 0; cj < ncj; cj++) acc[cj] = (floatx4){0.f,0.f,0.f,0.f};

    #pragma unroll
    for (int slab = 0; slab < nslab; slab++) {
        const int kk = slab*32 + quad*8;
        const float* src;
        if (MODE == 2 && kk >= DS) src = aux + (size_t)row*DD + (kk - DS);
        else                       src = Abase + (size_t)row*sA + kk;
        floatx4 va = *(const floatx4*)src;
        floatx4 vb = *(const floatx4*)(src + 4);
        if (BNA && MODE == 3 && seg == 0) {
            #pragma unroll
            for (int j = 0; j < 4; j++) {
                va[j] = fmaxf(fmaf(va[j], sbn[kk+j],   sbn[DS+kk+j]),   0.f);
                vb[j] = fmaxf(fmaf(vb[j], sbn[kk+4+j], sbn[DS+kk+4+j]), 0.f);
            }
        }
        short8 ahi, alo;
        #pragma unroll
        for (int j = 0; j < 4; j++) {
            unsigned short h = f2bf(va[j]);
            ahi[j] = (short)h; alo[j] = (short)f2bf(va[j] - bf2f(h));
        }
        #pragma unroll
        for (int j = 0; j < 4; j++) {
            unsigned short h = f2bf(vb[j]);
            ahi[4+j] = (short)h; alo[4+j] = (short)f2bf(vb[j] - bf2f(h));
        }
        const short8* bh = (const short8*)WhiS + (size_t)slab*ncj*64;
        const short8* bl = (const short8*)WloS + (size_t)slab*ncj*64;
        #pragma unroll
        for (int cj = 0; cj < ncj; cj++) {
            short8 bhv = bh[cj*64 + lane];
            short8 blv = bl[cj*64 + lane];
            acc[cj] = __builtin_amdgcn_mfma_f32_16x16x32_bf16(alo, bhv, acc[cj], 0, 0, 0);
            acc[cj] = __builtin_amdgcn_mfma_f32_16x16x32_bf16(ahi, blv, acc[cj], 0, 0, 0);
            acc[cj] = __builtin_amdgcn_mfma_f32_16x16x32_bf16(ahi, bhv, acc[cj], 0, 0, 0);
        }
    }
    const int rbase = blockIdx.x*64 + w*16 + quad*4;
    #pragma unroll
    for (int cj = 0; cj < ncj; cj++) {
        const float bb = bias ? bias[cj*16 + c] : 0.f;
        float s = 0.f, ss = 0.f;
        #pragma unroll
        for (int p = 0; p < 4; p++) {
            float v = acc[cj][p] + bb;
            if (MODE == 3) {
                if (seg > 0) {
                    float xv = Amat[(size_t)(rbase + p)*DS + cj*16 + c];
                    if (BNA) xv = fmaxf(fmaf(xv, sbn[cj*16+c], sbn[DS+cj*16+c]), 0.f);
                    if (seg == 1) v = xv - v;     // e = xd - k
                    else          v += xv;        // v2 = v + xd
                }
                CS16[(size_t)(rbase + p)*N + cj*16 + c] = f2bf(v);
            } else {
                CS[(size_t)(rbase + p)*N + cj*16 + c] = v;
            }
            if (STATS) { s += v; ss += v*v; }
        }
        if (STATS) {
            s  += __shfl_xor(s, 16);  s  += __shfl_xor(s, 32);
            ss += __shfl_xor(ss, 16); ss += __shfl_xor(ss, 32);
            if (quad == 0) {
                atomicAdd(&sstat[cj*16 + c], s);
                atomicAdd(&sstat[N + cj*16 + c], ss);
            }
        }
    }
    if (STATS) {
        __syncthreads();
        for (int i = t; i < N; i += 256) {
            atomicAdd(&sums[i],  sstat[i]);
            atomicAdd(&sumsq[i], sstat[N + i]);
        }
    }
}

// ------------------------------------------- MFMA h-GEMM + fused BN stats
// h row r = q[r>>4] + e[nidx[r]]  (q, e in bf16)
__global__ __launch_bounds__(256) void k_gemm_h(
    const unsigned short* __restrict__ q, const unsigned short* __restrict__ e,
    const int* __restrict__ nidx,
    const unsigned short* __restrict__ W1sw, const float* __restrict__ b1,
    unsigned short* __restrict__ hpre,
    float* __restrict__ sums, float* __restrict__ sumsq)
{
    __shared__ unsigned short WF[16384];
    __shared__ unsigned short outT[128*128];
    __shared__ float sstat[256];
    const int t = threadIdx.x;
    const int w = t >> 6, lane = t & 63;
    sstat[t] = 0.f;
    #pragma unroll
    for (int i = 0; i < 8; i++)
        ((uint4*)WF)[t + 256*i] = ((const uint4*)W1sw)[t + 256*i];
    __syncthreads();

    const int quad = lane >> 4, c = lane & 15;
    const int r0 = blockIdx.x * 128 + w * 32;
    const int nid0 = nidx[r0 + c];
    const int nid1 = nidx[r0 + 16 + c];
    const int pr0 = r0 >> 4;
    const int pr1 = pr0 + 1;

    floatx4 acc[2][8];
    #pragma unroll
    for (int ti = 0; ti < 2; ti++)
        #pragma unroll
        for (int cj = 0; cj < 8; cj++)
            acc[ti][cj] = (floatx4){0.f, 0.f, 0.f, 0.f};

    for (int ks = 0; ks < 4; ks++) {
        short8 bf[8];
        #pragma unroll
        for (int cj = 0; cj < 8; cj++)
            bf[cj] = ((const short8*)WF)[(ks*8 + cj)*64 + lane];
        const int ko = ks*32 + quad*8;
        #pragma unroll
        for (int ti = 0; ti < 2; ti++) {
            const int pr = ti ? pr1 : pr0;
            const int m  = ti ? nid1 : nid0;
            uint4 qv = *(const uint4*)(q + (size_t)pr*DS + ko);
            uint4 ev = *(const uint4*)(e + (size_t)m*DS + ko);
            unsigned qw[4] = {qv.x, qv.y, qv.z, qv.w};
            unsigned ew[4] = {ev.x, ev.y, ev.z, ev.w};
            short8 af;
            #pragma unroll
            for (int j = 0; j < 4; j++) {
                float f0 = bf2f((unsigned short)(qw[j] & 0xffffu))
                         + bf2f((unsigned short)(ew[j] & 0xffffu));
                float f1 = bf2f((unsigned short)(qw[j] >> 16))
                         + bf2f((unsigned short)(ew[j] >> 16));
                af[2*j]   = (short)f2bf(f0);
                af[2*j+1] = (short)f2bf(f1);
            }
            #pragma unroll
            for (int cj = 0; cj < 8; cj++)
                acc[ti][cj] = __builtin_amdgcn_mfma_f32_16x16x32_bf16(af, bf[cj], acc[ti][cj], 0, 0, 0);
        }
    }

    #pragma unroll
    for (int cj = 0; cj < 8; cj++) {
        const float bb = b1[cj*16 + c];
        float s = 0.f, ss = 0.f;
        #pragma unroll
        for (int ti = 0; ti < 2; ti++)
            #pragma unroll
            for (int p = 0; p < 4; p++) {
                float v = acc[ti][cj][p] + bb;
                s += v; ss += v*v;
                int lr = w*32 + ti*16 + quad*4 + p;
                outT[lr*128 + cj*16 + c] = f2bf(v);
            }
        s  += __shfl_xor(s, 16);  s  += __shfl_xor(s, 32);
        ss += __shfl_xor(ss, 16); ss += __shfl_xor(ss, 32);
        if (quad == 0) {
            atomicAdd(&sstat[cj*16 + c], s);
            atomicAdd(&sstat[128 + cj*16 + c], ss);
        }
    }
    __syncthreads();
    unsigned short* gdst = hpre + (size_t)blockIdx.x * 128 * 128;
    #pragma unroll
    for (int i = 0; i < 8; i++)
        ((uint4*)gdst)[t + 256*i] = ((const uint4*)outT)[t + 256*i];
    if (t < 128) atomicAdd(&sums[t], sstat[t]);
    else         atomicAdd(&sumsq[t - 128], sstat[t]);
}

// --------- MFMA attn: inline BN finalize -> bn+relu -> sim -> softmax -> agg
__global__ __launch_bounds__(256) void k_attn2(
    const unsigned short* __restrict__ hpre, const float* __restrict__ sums_h,
    const float* __restrict__ sumsq_h, const float* __restrict__ g1,
    const float* __restrict__ bt1, const unsigned short* __restrict__ W2sw,
    const unsigned short* __restrict__ v, const int* __restrict__ nidx,
    float* __restrict__ agg)
{
    __shared__ unsigned short WF[16384];
    __shared__ float s_sc[DS], s_sh[DS];
    const int t = threadIdx.x;
    #pragma unroll
    for (int i = 0; i < 8; i++)
        ((uint4*)WF)[t + 256*i] = ((const uint4*)W2sw)[t + 256*i];
    if (t < DS) {
        const float invM = 1.f / (float)MH;
        float m   = sums_h[t] * invM;
        float var = sumsq_h[t] * invM - m*m;
        float sc  = g1[t] * rsqrtf(var + 1e-5f);
        s_sc[t] = sc;
        s_sh[t] = bt1[t] - m * sc;
    }
    __syncthreads();

    const int w = t >> 6, lane = t & 63;
    const int gp = blockIdx.x * 4 + w;
    const int quad = lane >> 4, c = lane & 15;

    floatx4 acc[8];
    #pragma unroll
    for (int cj = 0; cj < 8; cj++) acc[cj] = (floatx4){0.f, 0.f, 0.f, 0.f};

    for (int ks = 0; ks < 4; ks++) {
        const int ko = ks*32 + quad*8;
        const unsigned short* hp = hpre + ((size_t)gp*16 + c)*DS + ko;
        uint4 hv = *(const uint4*)hp;
        floatx4 sc0 = *(const floatx4*)&s_sc[ko];
        floatx4 sc1 = *(const floatx4*)&s_sc[ko + 4];
        floatx4 sh0 = *(const floatx4*)&s_sh[ko];
        floatx4 sh1 = *(const floatx4*)&s_sh[ko + 4];
        unsigned int hw[4] = {hv.x, hv.y, hv.z, hv.w};
        short8 af;
        #pragma unroll
        for (int j = 0; j < 4; j++) {
            unsigned short u0 = (unsigned short)(hw[j] & 0xffffu);
            unsigned short u1 = (unsigned short)(hw[j] >> 16);
            float f0 = fmaxf(fmaf(bf2f(u0), (j<2)?sc0[2*j]:sc1[2*j-4],   (j<2)?sh0[2*j]:sh1[2*j-4]),   0.f);
            float f1 = fmaxf(fmaf(bf2f(u1), (j<2)?sc0[2*j+1]:sc1[2*j-3], (j<2)?sh0[2*j+1]:sh1[2*j-3]), 0.f);
            af[2*j]   = (short)f2bf(f0);
            af[2*j+1] = (short)f2bf(f1);
        }
        #pragma unroll
        for (int cj = 0; cj < 8; cj++) {
            short8 bfv = ((const short8*)WF)[(ks*8 + cj)*64 + lane];
            acc[cj] = __builtin_amdgcn_mfma_f32_16x16x32_bf16(af, bfv, acc[cj], 0, 0, 0);
        }
    }

    int nid[4];
    #pragma unroll
    for (int p = 0; p < 4; p++) nid[p] = nidx[gp*16 + quad*4 + p];

    #pragma unroll
    for (int cj = 0; cj < 8; cj++) {
        float m4 = fmaxf(fmaxf(acc[cj][0], acc[cj][1]), fmaxf(acc[cj][2], acc[cj][3]));
        m4 = fmaxf(m4, __shfl_xor(m4, 16));
        m4 = fmaxf(m4, __shfl_xor(m4, 32));
        float e[4]; float s4 = 0.f;
        #pragma unroll
        for (int p = 0; p < 4; p++) { e[p] = __expf(acc[cj][p] - m4); s4 += e[p]; }
        s4 += __shfl_xor(s4, 16); s4 += __shfl_xor(s4, 32);
        const float inv = 1.f / s4;
        const int col = cj*16 + c;
        float a = 0.f;
        #pragma unroll
        for (int p = 0; p < 4; p++)
            a = fmaf(e[p]*inv, bf2f(v[(size_t)nid[p]*DS + col]), a);
        a += __shfl_xor(a, 16); a += __shfl_xor(a, 32);
        if (quad == 0) agg[(size_t)gp*DS + col] = a;
    }
}

// bn+relu, float4-vectorized, inline finalize (memory-bound; output mlp only)
__global__ __launch_bounds__(256) void k_bnrelu(
    const float4* __restrict__ X, const float* __restrict__ sums,
    const float* __restrict__ sumsq, const float* __restrict__ g,
    const float* __restrict__ bt, float invM,
    float4* __restrict__ Y, size_t total4, int N)
{
    size_t i = (size_t)blockIdx.x * 256 + threadIdx.x;
    if (i < total4) {
        int c = (int)((i*4) & (size_t)(N - 1));
        float4 sm = *(const float4*)(sums + c);
        float4 sq = *(const float4*)(sumsq + c);
        float4 gg = *(const float4*)(g + c);
        float4 bb = *(const float4*)(bt + c);
        float4 x = X[i], y;
        float m0 = sm.x*invM, m1 = sm.y*invM, m2 = sm.z*invM, m3 = sm.w*invM;
        float s0 = gg.x*rsqrtf(sq.x*invM - m0*m0 + 1e-5f);
        float s1 = gg.y*rsqrtf(sq.y*invM - m1*m1 + 1e-5f);
        float s2 = gg.z*rsqrtf(sq.z*invM - m2*m2 + 1e-5f);
        float s3 = gg.w*rsqrtf(sq.w*invM - m3*m3 + 1e-5f);
        y.x = fmaxf(fmaf(x.x, s0, bb.x - m0*s0), 0.f);
        y.y = fmaxf(fmaf(x.y, s1, bb.y - m1*s1), 0.f);
        y.z = fmaxf(fmaf(x.z, s2, bb.z - m2*s2), 0.f);
        y.w = fmaxf(fmaf(x.w, s3, bb.w - m3*s3), 0.f);
        Y[i] = y;
    }
}

// ------- cooperative radix-select top-K, 2 queries/block, FUSED phases (R12)
template<int NCAND, int KSEL, int EPI>
__global__ __launch_bounds__(256) void k_sel(
    const float4* __restrict__ qpts4, const float4* __restrict__ cpts4,
    int* __restrict__ nidx, const float* __restrict__ x2, float* __restrict__ xi)
{
    __shared__ unsigned hist0[1024], hist1[1024];
    __shared__ unsigned skey[2][64];
    __shared__ unsigned sidx[2][64];
    __shared__ float    swtE[2][KSEL];
    __shared__ unsigned sidxE[2][KSEL];
    __shared__ unsigned wpart[2][4];
    __shared__ int      sstate[20];

    const int gp0 = blockIdx.x * 2;
    const int b = gp0 >> 12;
    const int t = threadIdx.x, wv = t >> 6, lane = t & 63;
    constexpr int ITER = NCAND / 256;

    const float4 qv0 = qpts4[gp0];
    const float4 qv1 = qpts4[gp0 + 1];
    const float4* pb = cpts4 + (size_t)b*NCAND;

    unsigned kreg[2][ITER];
    ((uint4*)hist0)[t] = (uint4){0u,0u,0u,0u};
    ((uint4*)hist1)[t] = (uint4){0u,0u,0u,0u};
    __syncthreads();
    #pragma unroll
    for (int it = 0; it < ITER; it++) {
        int j = t + 256*it;
        float4 cv = pb[j];
        float dot0 = fmaf(qv0.z, cv.z, fmaf(qv0.y, cv.y, qv0.x*cv.x));
        float dot1 = fmaf(qv1.z, cv.z, fmaf(qv1.y, cv.y, qv1.x*cv.x));
        float d20 = fmaxf(fmaf(-2.f, dot0, qv0.w + cv.w), 0.f);
        float d21 = fmaxf(fmaf(-2.f, dot1, qv1.w + cv.w), 0.f);
        unsigned k0 = (unsigned)(d20 * KSCALE);
        unsigned k1 = (unsigned)(d21 * KSCALE);
        kreg[0][it] = k0; kreg[1][it] = k1;
        atomicAdd(&hist0[k0 >> 20], 1u);
        atomicAdd(&hist1[k1 >> 20], 1u);
    }
    __syncthreads();

    uint4 h40 = ((const uint4*)hist0)[t];
    uint4 h41 = ((const uint4*)hist1)[t];
    unsigned hv0[4] = {h40.x, h40.y, h40.z, h40.w};
    unsigned hv1[4] = {h41.x, h41.y, h41.z, h41.w};
    unsigned tsum0 = hv0[0]+hv0[1]+hv0[2]+hv0[3];
    unsigned tsum1 = hv1[0]+hv1[1]+hv1[2]+hv1[3];
    unsigned incl0 = tsum0, incl1 = tsum1;
    #pragma unroll
    for (int off = 1; off < 64; off <<= 1) {
        unsigned o0 = (unsigned)__shfl_up((int)incl0, off);
        unsigned o1 = (unsigned)__shfl_up((int)incl1, off);
        if (lane >= off) { incl0 += o0; incl1 += o1; }
    }
    if (lane == 63) { wpart[0][wv] = incl0; wpart[1][wv] = incl1; }
    __syncthreads();
    unsigned wbase0 = 0, wbase1 = 0;
    for (int i2 = 0; i2 < wv; i2++) { wbase0 += wpart[0][i2]; wbase1 += wpart[1][i2]; }
    const unsigned excl0 = wbase0 + incl0 - tsum0;
    const unsigned excl1 = wbase1 + incl1 - tsum1;
    if ((int)excl0 < KSEL && KSEL <= (int)(excl0 + tsum0)) {
        unsigned cum = excl0;
        #pragma unroll
        for (int i2 = 0; i2 < 4; i2++) {
            unsigned h = hv0[i2];
            if ((int)cum < KSEL && KSEL <= (int)(cum + h)) {
                sstate[0] = t*4 + i2; sstate[1] = (int)cum; sstate[2] = (int)h;
                sstate[3] = ((int)cum + (int)h <= 64) ? 1 : 0; sstate[4] = 0;
                break;
            }
            cum += h;
        }
    }
    if ((int)excl1 < KSEL && KSEL <= (int)(excl1 + tsum1)) {
        unsigned cum = excl1;
        #pragma unroll
        for (int i2 = 0; i2 < 4; i2++) {
            unsigned h = hv1[i2];
            if ((int)cum < KSEL && KSEL <= (int)(cum + h)) {
                sstate[8] = t*4 + i2; sstate[9] = (int)cum; sstate[10] = (int)h;
                sstate[11] = ((int)cum + (int)h <= 64) ? 1 : 0; sstate[12] = 0;
                break;
            }
            cum += h;
        }
    }
    __syncthreads();

    if (sstate[3] == 1 && sstate[11] == 1) {
        const unsigned P0 = (unsigned)sstate[0];
        const unsigned P1 = (unsigned)sstate[8];
        const unsigned long long lmask = (1ull << lane) - 1ull;
        #pragma unroll
        for (int it = 0; it < ITER; it++) {
            int j = t + 256*it;
            unsigned k0 = kreg[0][it], k1 = kreg[1][it];
            bool f0 = ((k0 >> 20) <= P0);
            bool f1 = ((k1 >> 20) <= P1);
            unsigned long long bal0 = __ballot(f0);
            unsigned long long bal1 = __ballot(f1);
            int w0 = __popcll(bal0), w1 = __popcll(bal1);
            int b0 = 0, b1 = 0;
            if (lane == 0 && w0) b0 = atomicAdd((unsigned*)&sstate[4], (unsigned)w0);
            if (lane == 0 && w1) b1 = atomicAdd((unsigned*)&sstate[12], (unsigned)w1);
            b0 = __shfl(b0, 0); b1 = __shfl(b1, 0);
            if (f0) { int pos = b0 + __popcll(bal0 & lmask); skey[0][pos] = k0; sidx[0][pos] = (unsigned)j; }
            if (f1) { int pos = b1 + __popcll(bal1 & lmask); skey[1][pos] = k1; sidx[1][pos] = (unsigned)j; }
        }
    } else {
        #pragma unroll
        for (int qi = 0; qi < 2; qi++) {
            const float4 qv = qi ? qv1 : qv0;
            unsigned P = (unsigned)sstate[qi*8+0];
            int S = sstate[qi*8+1], cntB = sstate[qi*8+2], mode = sstate[qi*8+3];
            int gsh = 20;
            if (mode == 0) {
                for (int round = 1; round < 4; round++) {
                    const int nb  = (round == 3) ? 16 : 256;
                    const int wb  = (round == 3) ? 4 : 8;
                    const int sh  = (round == 1) ? 12 : (round == 2 ? 4 : 0);
                    const int psh = sh + wb;
                    if (t < nb) hist0[t] = 0u;
                    __syncthreads();
                    #pragma unroll
                    for (int it = 0; it < ITER; it++) {
                        unsigned key = kreg[qi][it];
                        if ((key >> psh) == P)
                            atomicAdd(&hist0[(key >> sh) & (nb - 1)], 1u);
                    }
                    __syncthreads();
                    unsigned hv = (t < nb) ? hist0[t] : 0u;
                    unsigned tsum = hv;
                    unsigned incl = tsum;
                    #pragma unroll
                    for (int off = 1; off < 64; off <<= 1) {
                        unsigned o = (unsigned)__shfl_up((int)incl, off);
                        if (lane >= off) incl += o;
                    }
                    if (lane == 63) wpart[0][wv] = incl;
                    __syncthreads();
                    unsigned wbase = 0;
                    for (int i2 = 0; i2 < wv; i2++) wbase += wpart[0][i2];
                    unsigned exclT = wbase + incl - tsum;
                    const int need = KSEL - S;
                    if ((int)exclT < need && need <= (int)(exclT + tsum)) {
                        int Snew = S + (int)exclT;
                        int tot  = Snew + (int)tsum;
                        sstate[qi*8+0] = (int)((P << wb) | (unsigned)t);
                        sstate[qi*8+1] = Snew; sstate[qi*8+2] = (int)tsum;
                        sstate[qi*8+3] = (tot <= 64) ? 1 : ((round == 3) ? 2 : 0);
                        sstate[qi*8+4] = 0;
                    }
                    __syncthreads();
                    P = (unsigned)sstate[qi*8+0]; S = sstate[qi*8+1];
                    cntB = sstate[qi*8+2]; mode = sstate[qi*8+3];
                    gsh = sh;
                    if (mode) break;
                }
            }
            if (mode == 1) {
                const unsigned long long lmask = (1ull << lane) - 1ull;
                #pragma unroll
                for (int it = 0; it < ITER; it++) {
                    int j = t + 256*it;
                    unsigned key = kreg[qi][it];
                    bool f = ((key >> gsh) <= P);
                    unsigned long long bal = __ballot(f);
                    int wcnt = __popcll(bal);
                    int base = 0;
                    if (lane == 0 && wcnt) base = atomicAdd((unsigned*)&sstate[qi*8+4], (unsigned)wcnt);
                    base = __shfl(base, 0);
                    if (f) {
                        int pos = base + __popcll(bal & lmask);
                        skey[qi][pos] = key; sidx[qi][pos] = (unsigned)j;
                    }
                }
            } else {
                if (t < 64) {
                    const unsigned long long lmask = (1ull << lane) - 1ull;
                    int cnt = 0;
                    for (int pass = 0; pass < 2; pass++) {
                        for (int it = 0; it < NCAND/64; it++) {
                            int j = lane + 64*it;
                            float4 cv = pb[j];
                            float dot = fmaf(qv.z, cv.z, fmaf(qv.y, cv.y, qv.x*cv.x));
                            float d2 = fmaxf(fmaf(-2.f, dot, qv.w + cv.w), 0.f);
                            unsigned key = (unsigned)(d2 * KSCALE);
                            bool f = pass ? (key == P) : (key < P);
                            unsigned long long bal = __ballot(f);
                            if (f) {
                                int pos = cnt + __popcll(bal & lmask);
                                if (pos < 64) { skey[qi][pos] = key; sidx[qi][pos] = (unsigned)j; }
                            }
                            cnt += __popcll(bal);
                        }
                    }
                    if (lane == 0) { sstate[qi*8+1] = min(cnt, 64); sstate[qi*8+2] = 0; }
                }
            }
            __syncthreads();
        }
    }
    __syncthreads();

    if (wv < 2) {
        const int q = wv;
        const int total = sstate[q*8+1] + sstate[q*8+2];
        unsigned long long v = ~0ull;
        if (lane < total)
            v = (((unsigned long long)skey[q][lane]) << 32) | sidx[q][lane];
        #pragma unroll
        for (int k = 2; k <= 64; k <<= 1) {
            #pragma unroll
            for (int jj = k >> 1; jj > 0; jj >>= 1) {
                unsigned long long p = shfl_xor_u64(v, jj);
                bool up = ((lane & k) == 0);
                bool takeMin = (((lane & jj) == 0) == up);
                bool pl = p < v;
                v = (takeMin == pl) ? p : v;
            }
        }
        if (EPI == 0) {
            if (lane < KSEL)
                nidx[(gp0 + q)*KSEL + lane] = b*NCAND + (int)(v & 0xffffffffull);
        } else {
            const float4 qq = q ? qv1 : qv0;
            float wgt = 0.f;
            unsigned si = (unsigned)(v & 0xffffffffull);
            if (lane < KSEL) {
                float4 cv = pb[si];
                float dot = fmaf(qq.z, cv.z, fmaf(qq.y, cv.y, qq.x*cv.x));
                float d2 = fmaxf(fmaf(-2.f, dot, qq.w + cv.w), 0.f);
                wgt = 1.f / (sqrtf(d2) + 1e-8f);
            }
            float ws = wgt;
            ws += __shfl_xor(ws, 1); ws += __shfl_xor(ws, 2); ws += __shfl_xor(ws, 4);
            if (lane < KSEL) {
                swtE[q][lane]  = wgt / ws;
                sidxE[q][lane] = si;
            }
        }
    }

    if (EPI == 1) {
        __syncthreads();
        const int qi2 = t >> 7, tt = t & 127;
        const float* x2b = x2 + (size_t)b*NCAND*DS;
        float a = 0.f;
        #pragma unroll
        for (int r = 0; r < KSEL; r++)
            a = fmaf(swtE[qi2][r], x2b[(size_t)sidxE[qi2][r]*DS + tt], a);
        xi[(size_t)(gp0 + qi2)*DS + tt] = a;
    }
}

// ---------------------------------------------------------------- launch
extern "C" void kernel_launch(void* const* d_in, const int* in_sizes, int n_in,
                              void* d_out, int out_size, void* d_ws, size_t ws_size,
                              hipStream_t stream)
{
    const float* p1 = (const float*)d_in[0];
    const float* x1 = (const float*)d_in[1];
    const int*   o1 = (const int*)d_in[2];
    const float* p2 = (const float*)d_in[3];
    const float* x2 = (const float*)d_in[4];
    const float* W_dense = (const float*)d_in[7];
    const float* b_dense = (const float*)d_in[8];
    const float* g_dense = (const float*)d_in[9];
    const float* bt_dense= (const float*)d_in[10];
    const float* Wq = (const float*)d_in[11];
    const float* Wk = (const float*)d_in[12];
    const float* Wv = (const float*)d_in[13];
    const float* W1 = (const float*)d_in[14];
    const float* b1 = (const float*)d_in[15];
    const float* g1 = (const float*)d_in[16];
    const float* bt1= (const float*)d_in[17];
    const float* W2 = (const float*)d_in[18];
    const float* W_out = (const float*)d_in[20];
    const float* b_out = (const float*)d_in[21];
    const float* g_out = (const float*)d_in[22];
    const float* bt_out= (const float*)d_in[23];

    float* ws   = (float*)d_ws;
    unsigned short* hpre = (unsigned short*)(ws + OFF_HPRE);
    unsigned short* wts  = (unsigned short*)(ws + OFF_WTS);
    float* tmp  = ws + OFF_TMP;
    float* xi   = ws + OFF_XI;
    float* qm   = ws + OFF_Q;
    float* outp = ws + OFF_OUTP;
    int*   nidx = (int*)(ws + OFF_NIDX);
    float* stat = ws + OFF_STAT;
    float4* p1q = (float4*)(ws + OFF_P1Q);
    float4* p2q = (float4*)(ws + OFF_P2Q);
    unsigned short* q16 = (unsigned short*)(ws + OFF_Q);
    unsigned short* e16 = (unsigned short*)(ws + OFF_K);
    unsigned short* v16 = (unsigned short*)(ws + OFF_V);
    float* sums_d = stat,      *sumsq_d = stat+256;
    float* sums_h = stat+1024, *sumsq_h = stat+1280;
    float* sums_o = stat+2048, *sumsq_o = stat+2304;
    float* out = (float*)d_out;

    // prolog + weight swizzles, one launch
    SwzParams sp;
    sp.W[0]=W_dense; sp.W[1]=Wq; sp.W[2]=Wk; sp.W[3]=Wv; sp.W[4]=W1; sp.W[5]=W2; sp.W[6]=W_out;
    sp.hi[0]=wts+WDH; sp.hi[1]=wts+WQH; sp.hi[2]=wts+WKH; sp.hi[3]=wts+WVH;
    sp.hi[4]=wts+W1H; sp.hi[5]=wts+W2H; sp.hi[6]=wts+WOH;
    sp.lo[0]=wts+WDL; sp.lo[1]=wts+WQL; sp.lo[2]=wts+WKL; sp.lo[3]=wts+WVL;
    sp.lo[4]=wts+W1L; sp.lo[5]=wts+W2L; sp.lo[6]=wts+WOL;
    sp.N[0]=128; sp.N[1]=128; sp.N[2]=128; sp.N[3]=128; sp.N[4]=128; sp.N[5]=128; sp.N[6]=256;
    sp.fid0[0]=0; sp.fid0[1]=16; sp.fid0[2]=48; sp.fid0[3]=80; sp.fid0[4]=112;
    sp.fid0[5]=144; sp.fid0[6]=176; sp.fid0[7]=272;
    k_prolog<<<NPRO + 68, 256, 0, stream>>>(p1, o1, p2, out, stat, p1q, p2q, sp);

    // dense_mlp GEMM (stats fused); bn+relu applied on-the-fly inside qkv
    k_gemm_mf<128,64,0,1,0><<<M1/64, 256, 0, stream>>>(x1, wts+WDH, wts+WDL, b_dense, tmp,
        nullptr, sums_d, sumsq_d, nullptr, nullptr, nullptr, nullptr);

    // interpolation (2 queries/block fused radix select, K=8)
    k_sel<NN2, KI, 1><<<M1/2, 256, 0, stream>>>(p1q, p2q, nullptr, x2, xi);

    // q, k, v projections — one launch; BN(dense) fused into A reads;
    // bf16 outputs: q / e=xd-k / v2=v+xd
    k_gemm_mf<128,128,3,0,1><<<dim3(M1/64,3), 256, 0, stream>>>(tmp, wts+WQH, wts+WQL,
        nullptr, qm, xi, nullptr, nullptr, sums_d, sumsq_d, g_dense, bt_dense);

    // kNN-16 (2 queries/block fused radix select)
    k_sel<NN1, KN, 0><<<M1/2, 256, 0, stream>>>(p1q, p1q, nidx, nullptr, nullptr);

    // h-GEMM (MFMA, fused BN stats, bf16 q+e streams) -> hpre bf16
    k_gemm_h<<<MH/128, 256, 0, stream>>>(q16, e16, nidx, wts+W1H, b1, hpre, sums_h, sumsq_h);

    // attn (MFMA, BN finalize inline, bf16 v2)
    k_attn2<<<M1/4, 256, 0, stream>>>(hpre, sums_h, sumsq_h, g1, bt1, wts+W2H, v16, nidx, tmp);

    // output mlp (stats fused) -> bn+relu (finalize inline, float4)
    k_gemm_mf<256,192,2,1,0><<<M1/64, 256, 0, stream>>>(tmp, wts+WOH, wts+WOL, b_out, outp,
        x1, sums_o, sumsq_o, nullptr, nullptr, nullptr, nullptr);
    k_bnrelu<<<(M1*DOUT/4)/256, 256, 0, stream>>>((const float4*)outp, sums_o, sumsq_o,
        g_out, bt_out, 1.f/(float)M1, (float4*)(out + OUT_X), (size_t)M1*DOUT/4, DOUT);
}